// Round 1
// baseline (333.010 us; speedup 1.0000x reference)
//
#include <hip/hip_runtime.h>

#define B_ 128
#define N_ 64
#define T_ 1000
#define H_ 16
#define TPAD 1014   // 7 zeros + 1000 + 7 zeros

// ---------------- A: energy[b,i] = var(x[b,0,i,:], ddof=1) ----------------
__global__ void k_energy(const float* __restrict__ x, float* __restrict__ energy) {
    int row = blockIdx.x;                       // b*64 + i
    const float* xr = x + (size_t)row * T_;
    float s = 0.f, s2 = 0.f;
    for (int t = threadIdx.x; t < T_; t += 256) {
        float v = xr[t];
        s += v; s2 += v * v;
    }
    __shared__ float r1[256], r2[256];
    r1[threadIdx.x] = s; r2[threadIdx.x] = s2;
    __syncthreads();
    for (int off = 128; off > 0; off >>= 1) {
        if (threadIdx.x < off) {
            r1[threadIdx.x] += r1[threadIdx.x + off];
            r2[threadIdx.x] += r2[threadIdx.x + off];
        }
        __syncthreads();
    }
    if (threadIdx.x == 0) {
        float S = r1[0], S2 = r2[0];
        energy[row] = (S2 - S * S / (float)T_) / (float)(T_ - 1);
    }
}

// ---------------- B: attn + diag-mask + softmax -> w (written to d_out) ----
__global__ void k_attn_softmax(const float* __restrict__ energy,
                               const float* __restrict__ q_w, const float* __restrict__ q_b,
                               const float* __restrict__ k_w, const float* __restrict__ k_b,
                               float* __restrict__ wout) {
    int row = blockIdx.x;                       // b*64 + i
    int b = row >> 6, i = row & 63;
    int j = threadIdx.x;                        // 64 threads
    float ei = energy[b * 64 + i];
    float ej = energy[b * 64 + j];
    float a = 0.f;
    #pragma unroll
    for (int h = 0; h < H_; ++h)
        a += (ei * q_w[h] + q_b[h]) * (ej * k_w[h] + k_b[h]);
    a *= 0.25f;                                 // H^(-1/2), H=16
    if (j == i) a = -1e9f;
    float m = a;
    #pragma unroll
    for (int mask = 32; mask; mask >>= 1) m = fmaxf(m, __shfl_xor(m, mask));
    float p = __expf(a - m);
    float s = p;
    #pragma unroll
    for (int mask = 32; mask; mask >>= 1) s += __shfl_xor(s, mask);
    wout[(size_t)row * 64 + j] = p / s;
}

// ---------------- C: z_gcn = w @ xs + x  (stored in ws) --------------------
#define TC 100
__global__ void k_zgcn(const float* __restrict__ wmat, const float* __restrict__ x,
                       float* __restrict__ zg) {
    int b = blockIdx.y;
    int t0 = blockIdx.x * TC;
    __shared__ float wsh[64 * 64];
    __shared__ float xs[64][TC];
    const float* wb = wmat + (size_t)b * 64 * 64;
    for (int idx = threadIdx.x; idx < 4096; idx += 256) wsh[idx] = wb[idx];
    const float* xb = x + (size_t)b * 64 * T_;
    for (int idx = threadIdx.x; idx < 64 * TC; idx += 256) {
        int jj = idx / TC, tt = idx % TC;
        xs[jj][tt] = xb[jj * T_ + t0 + tt];
    }
    __syncthreads();
    for (int idx = threadIdx.x; idx < 64 * TC; idx += 256) {
        int ii = idx / TC, tt = idx % TC;
        float acc = 0.f;
        #pragma unroll 8
        for (int jj = 0; jj < 64; ++jj) acc += wsh[ii * 64 + jj] * xs[jj][tt];
        zg[(size_t)b * 64 * T_ + ii * T_ + t0 + tt] = acc + xb[ii * T_ + t0 + tt];
    }
}

// ------- shared conv helper pattern is inlined in D and F (15-tap sliding window) -------

// ---------------- D: BN statistics (sum, sumsq per channel) ----------------
__global__ void k_stats(const float* __restrict__ zg, const float* __restrict__ conv_w,
                        const float* __restrict__ conv_b, double* __restrict__ stats) {
    __shared__ float rows[16 * TPAD];           // 64896 B
    int h = threadIdx.x & 15, r = threadIdx.x >> 4;
    int row0 = blockIdx.x * 16;
    for (int idx = threadIdx.x; idx < 16 * TPAD; idx += 256) {
        int rr = idx / TPAD, j = idx - rr * TPAD;
        float v = 0.f;
        if (j >= 7 && j < 7 + T_) v = zg[(size_t)(row0 + rr) * T_ + (j - 7)];
        rows[idx] = v;
    }
    __syncthreads();
    float tap[15];
    #pragma unroll
    for (int k = 0; k < 15; ++k) tap[k] = conv_w[h * 15 + k];
    float cb = conv_b[h];
    const float* p = rows + r * TPAD;
    float win[15];
    #pragma unroll
    for (int k = 0; k < 14; ++k) win[k] = p[k];
    float s1 = 0.f, s2 = 0.f;
    int t = 0;
    for (int mi = 0; mi < 66; ++mi) {           // 66*15 = 990
        #pragma unroll
        for (int u = 0; u < 15; ++u) {
            win[(u + 14) % 15] = p[t + u + 14];
            float o = 0.f;
            #pragma unroll
            for (int k = 0; k < 15; ++k) o += tap[k] * win[(u + k) % 15];
            float zb = o + cb;
            s1 += zb; s2 += zb * zb;
        }
        t += 15;
    }
    #pragma unroll
    for (int u = 0; u < 10; ++u) {              // tail t = 990..999
        win[(u + 14) % 15] = p[990 + u + 14];
        float o = 0.f;
        #pragma unroll
        for (int k = 0; k < 15; ++k) o += tap[k] * win[(u + k) % 15];
        float zb = o + cb;
        s1 += zb; s2 += zb * zb;
    }
    __syncthreads();
    rows[threadIdx.x] = s1;
    rows[256 + threadIdx.x] = s2;
    __syncthreads();
    if (threadIdx.x < 16) {
        int hh = threadIdx.x;
        float a1 = 0.f, a2 = 0.f;
        for (int rr = 0; rr < 16; ++rr) {
            a1 += rows[rr * 16 + hh];
            a2 += rows[256 + rr * 16 + hh];
        }
        atomicAdd(&stats[hh], (double)a1);
        atomicAdd(&stats[16 + hh], (double)a2);
    }
}

// ---------------- E: finalize BN scale/shift -------------------------------
__global__ void k_finalize(const double* __restrict__ stats, const float* __restrict__ gamma,
                           const float* __restrict__ beta, const float* __restrict__ conv_b,
                           float* __restrict__ scsh) {
    int h = threadIdx.x;
    if (h < 16) {
        double M = (double)B_ * N_ * T_;
        double mean = stats[h] / M;
        double var = stats[16 + h] / M - mean * mean;
        float sc = gamma[h] * (float)(1.0 / sqrt(var + 1e-5));
        float sh = beta[h] + (float)((double)conv_b[h] - mean) * sc;
        scsh[h] = sc; scsh[16 + h] = sh;
    }
}

// ---------------- F: conv + BN + ELU + LIF scan -> firing rate -------------
__global__ void k_scan(const float* __restrict__ zg, const float* __restrict__ conv_w,
                       const float* __restrict__ scsh, float* __restrict__ zfeat) {
    __shared__ float rows[16 * TPAD];
    int h = threadIdx.x & 15, r = threadIdx.x >> 4;
    int row0 = blockIdx.x * 16;
    for (int idx = threadIdx.x; idx < 16 * TPAD; idx += 256) {
        int rr = idx / TPAD, j = idx - rr * TPAD;
        float v = 0.f;
        if (j >= 7 && j < 7 + T_) v = zg[(size_t)(row0 + rr) * T_ + (j - 7)];
        rows[idx] = v;
    }
    __syncthreads();
    float tap[15];
    #pragma unroll
    for (int k = 0; k < 15; ++k) tap[k] = conv_w[h * 15 + k];
    float sc = scsh[h], sh = scsh[16 + h];
    const float* p = rows + r * TPAD;
    float win[15];
    #pragma unroll
    for (int k = 0; k < 14; ++k) win[k] = p[k];
    float v = 0.f, cnt = 0.f;
    int t = 0;
    for (int mi = 0; mi < 66; ++mi) {
        #pragma unroll
        for (int u = 0; u < 15; ++u) {
            win[(u + 14) % 15] = p[t + u + 14];
            float o = 0.f;
            #pragma unroll
            for (int k = 0; k < 15; ++k) o += tap[k] * win[(u + k) % 15];
            float zf = o * sc + sh;
            float a = zf > 0.f ? zf : (__expf(zf) - 1.f);   // ELU
            v = 0.5f * v + a;                                // leak (1 - 1/TAU) = 0.5
            float s = (v > 0.5f) ? 1.f : 0.f;                // spike(v - VTH)
            cnt += s;
            v -= 0.5f * s;                                   // reset by VTH
        }
        t += 15;
    }
    #pragma unroll
    for (int u = 0; u < 10; ++u) {
        win[(u + 14) % 15] = p[990 + u + 14];
        float o = 0.f;
        #pragma unroll
        for (int k = 0; k < 15; ++k) o += tap[k] * win[(u + k) % 15];
        float zf = o * sc + sh;
        float a = zf > 0.f ? zf : (__expf(zf) - 1.f);
        v = 0.5f * v + a;
        float s = (v > 0.5f) ? 1.f : 0.f;
        cnt += s;
        v -= 0.5f * s;
    }
    int row = row0 + r;
    int b = row >> 6, i = row & 63;
    zfeat[(size_t)b * 1024 + h * 64 + i] = cnt * (1.0f / (float)T_);
}

// ---------------- G: logits = z_feat @ fc_w.T + fc_b -----------------------
__global__ void k_fc(const float* __restrict__ zfeat, const float* __restrict__ fc_w,
                     const float* __restrict__ fc_b, float* __restrict__ logits) {
    int b = blockIdx.x;
    const float* zf = zfeat + (size_t)b * 1024;
    float a0 = 0.f, a1 = 0.f, a2 = 0.f, a3 = 0.f;
    for (int f = threadIdx.x; f < 1024; f += 256) {
        float z = zf[f];
        a0 += z * fc_w[f];
        a1 += z * fc_w[1024 + f];
        a2 += z * fc_w[2048 + f];
        a3 += z * fc_w[3072 + f];
    }
    __shared__ float red[4][256];
    red[0][threadIdx.x] = a0; red[1][threadIdx.x] = a1;
    red[2][threadIdx.x] = a2; red[3][threadIdx.x] = a3;
    __syncthreads();
    for (int off = 128; off > 0; off >>= 1) {
        if (threadIdx.x < off) {
            red[0][threadIdx.x] += red[0][threadIdx.x + off];
            red[1][threadIdx.x] += red[1][threadIdx.x + off];
            red[2][threadIdx.x] += red[2][threadIdx.x + off];
            red[3][threadIdx.x] += red[3][threadIdx.x + off];
        }
        __syncthreads();
    }
    if (threadIdx.x < 4) logits[b * 4 + threadIdx.x] = red[threadIdx.x][0] + fc_b[threadIdx.x];
}

extern "C" void kernel_launch(void* const* d_in, const int* in_sizes, int n_in,
                              void* d_out, int out_size, void* d_ws, size_t ws_size,
                              hipStream_t stream) {
    (void)in_sizes; (void)n_in; (void)out_size; (void)ws_size;
    const float* x      = (const float*)d_in[0];
    const float* q_w    = (const float*)d_in[1];
    const float* q_b    = (const float*)d_in[2];
    const float* k_w    = (const float*)d_in[3];
    const float* k_b    = (const float*)d_in[4];
    const float* conv_w = (const float*)d_in[5];
    const float* conv_b = (const float*)d_in[6];
    const float* bn_g   = (const float*)d_in[7];
    const float* bn_b   = (const float*)d_in[8];
    const float* fc_w   = (const float*)d_in[9];
    const float* fc_b   = (const float*)d_in[10];

    float* out    = (float*)d_out;
    float* logits = out;                        // 128*4
    float* zfeat  = out + 512;                  // 128*1024
    float* wmat   = out + 512 + 131072;         // 128*64*64

    char* ws      = (char*)d_ws;
    float* energy = (float*)ws;                               // 8192 f32
    float* zg     = (float*)(ws + 32768);                     // 8.192M f32
    double* stats = (double*)(ws + 32768 + 32768000);         // 32 f64
    float* scsh   = (float*)(ws + 32768 + 32768000 + 256);    // 32 f32

    k_energy<<<B_ * N_, 256, 0, stream>>>(x, energy);
    k_attn_softmax<<<B_ * N_, 64, 0, stream>>>(energy, q_w, q_b, k_w, k_b, wmat);
    dim3 gc(T_ / TC, B_);
    k_zgcn<<<gc, 256, 0, stream>>>(wmat, x, zg);
    hipMemsetAsync(stats, 0, 32 * sizeof(double), stream);
    k_stats<<<B_ * N_ / 16, 256, 0, stream>>>(zg, conv_w, conv_b, stats);
    k_finalize<<<1, 64, 0, stream>>>(stats, bn_g, bn_b, conv_b, scsh);
    k_scan<<<B_ * N_ / 16, 256, 0, stream>>>(zg, conv_w, scsh, zfeat);
    k_fc<<<B_, 256, 0, stream>>>(zfeat, fc_w, fc_b, logits);
}